// Round 2
// baseline (434.921 us; speedup 1.0000x reference)
//
#include <hip/hip_runtime.h>
#include <cstddef>
#include <cstdint>

#define BT   8192   // B*T tokens
#define HD   2048   // hidden
#define NS   32     // schemas
#define RDIM 16     // low rank
#define AD   32     // attr dim
#define CAP  2048   // per-(slot,schema) list capacity (expected ~256)

#define RT_M 32     // router tokens per block
#define EX_T 16     // expert tokens per chunk
#define HPAD 260    // padded LDS row stride (floats): 260 % 32 = 4 -> <=2-way on h/V reads

// async global->LDS, 16B per lane, wave-uniform LDS base (lane*16 appended by HW)
__device__ __forceinline__ void gld16(const float* g, float* l) {
    __builtin_amdgcn_global_load_lds(
        (const __attribute__((address_space(1))) unsigned int*)g,
        (__attribute__((address_space(3))) unsigned int*)l, 16, 0, 0);
}

__device__ __forceinline__ float dot4(const float4 a, const float4 b) {
    return a.x * b.x + a.y * b.y + a.z * b.z + a.w * b.w;
}
__device__ __forceinline__ void fma4(float4& o, const float a, const float4 b) {
    o.x += a * b.x; o.y += a * b.y; o.z += a * b.z; o.w += a * b.w;
}

__global__ void k_zero(int* __restrict__ cnt) {
    if (threadIdx.x < 64) cnt[threadIdx.x] = 0;
}

// ---------------- router ----------------
// 256 blocks x 32 tokens. Thread owns (2 tokens x 2 schemas), full K in regs.
// h staged via async GLD double-buffer; Wr read from global (L1/L2-resident).
__global__ __launch_bounds__(256) void k_router(
    const float* __restrict__ h, const float* __restrict__ Wr,
    const float* __restrict__ attr, const float* __restrict__ Wa,
    int* __restrict__ cnt, int* __restrict__ tok_list, float* __restrict__ cf_list)
{
    __shared__ float hbuf[2][RT_M][HPAD];
    __shared__ float sc_s[RT_M][NS + 1];

    const int tid  = threadIdx.x;
    const int w    = tid >> 6, lane = tid & 63;
    const int tp   = tid >> 4;          // token pair 0..15
    const int sp   = tid & 15;          // schema pair 0..15
    const int t0   = blockIdx.x * RT_M;

    // prime chunk 0 (8 rows per wave)
    #pragma unroll
    for (int r = 0; r < 8; ++r) {
        const int row = w * 8 + r;
        gld16(h + (size_t)(t0 + row) * HD + lane * 4, &hbuf[0][row][0]);
    }
    __syncthreads();

    float a00 = 0.f, a01 = 0.f, a10 = 0.f, a11 = 0.f;

    #pragma unroll 1
    for (int c = 0; c < 8; ++c) {
        if (c < 7) {  // prefetch next j-chunk
            #pragma unroll
            for (int r = 0; r < 8; ++r) {
                const int row = w * 8 + r;
                gld16(h + (size_t)(t0 + row) * HD + (c + 1) * 256 + lane * 4,
                      &hbuf[(c + 1) & 1][row][0]);
            }
        }
        const float4* h0 = (const float4*)&hbuf[c & 1][2 * tp][0];
        const float4* h1 = (const float4*)&hbuf[c & 1][2 * tp + 1][0];
        const float4* w0 = (const float4*)(Wr + (size_t)(2 * sp) * HD + c * 256);
        const float4* w1 = (const float4*)(Wr + (size_t)(2 * sp + 1) * HD + c * 256);
        #pragma unroll 4
        for (int jq = 0; jq < 64; ++jq) {
            const float4 hv0 = h0[jq], hv1 = h1[jq];
            const float4 wv0 = w0[jq], wv1 = w1[jq];
            a00 += dot4(hv0, wv0);
            a01 += dot4(hv0, wv1);
            a10 += dot4(hv1, wv0);
            a11 += dot4(hv1, wv1);
        }
        __syncthreads();
    }

    sc_s[2 * tp    ][2 * sp    ] = a00;
    sc_s[2 * tp    ][2 * sp + 1] = a01;
    sc_s[2 * tp + 1][2 * sp    ] = a10;
    sc_s[2 * tp + 1][2 * sp + 1] = a11;
    __syncthreads();

    if (tid < RT_M) {
        const int t = tid;
        float m1 = -1e30f, m2 = -1e30f;
        int i1 = 0, i2 = 0;
        #pragma unroll 1
        for (int sI = 0; sI < NS; ++sI) {   // strict > keeps lowest index on ties (lax.top_k)
            const float v = sc_s[t][sI];
            if (v > m1) { m2 = m1; i2 = i1; m1 = v; i1 = sI; }
            else if (v > m2) { m2 = v; i2 = sI; }
        }
        float Z = 0.f;
        #pragma unroll 1
        for (int sI = 0; sI < NS; ++sI) Z += __expf(sc_s[t][sI] - m1);
        const float e2  = __expf(m2 - m1);
        // g = softmax(sc)*mask renormed by (sum + 1e-8): G_i = e_i / (e1+e2 + 1e-8*Z)
        const float den = 1.f + e2 + 1e-8f * Z;
        const float G1 = 1.f / den, G2 = e2 / den;
        float d1 = 0.f, d2 = 0.f;
        #pragma unroll 1
        for (int d = 0; d < AD; ++d) {
            d1 += attr[i1 * AD + d] * Wa[d];
            d2 += attr[i2 * AD + d] * Wa[d];
        }
        const float aw1 = 1.f / (1.f + __expf(-d1));
        const float aw2 = 1.f / (1.f + __expf(-d2));
        const float mult = 0.9f + 0.2f * (G1 * aw1 + G2 * aw2);
        const float c1 = G1 * mult, c2 = G2 * mult;
        const int gt = t0 + t;
        int p = atomicAdd(cnt + i1, 1);
        if (p < CAP) { tok_list[i1 * CAP + p] = gt; cf_list[i1 * CAP + p] = c1; }
        p = atomicAdd(cnt + NS + i2, 1);
        if (p < CAP) { tok_list[(NS + i2) * CAP + p] = gt; cf_list[(NS + i2) * CAP + p] = c2; }
    }
}

// ---------------- fused expert: (slot,schema)-grouped, 16-token chunks ----------------
// Phase A: acc y[t][k] = h[t,:] @ U[s,:,k], thread = (4 tok x 4 k x 16-way j-split),
//          h via async GLD dbuf, U transposed into LDS [k][j] via reg round-trip (dbuf).
// Reduce 16-way j-split through LDS, fold gate coeff.
// Phase B: out[t][:] (+)= y[t][:] @ V[s], V via async GLD dbuf, thread = (1 tok x 16 cols).
// slot 0 stores (argmax covers every token exactly once), slot 1 non-atomic RMW add.
__global__ __launch_bounds__(256) void k_expert(
    const float* __restrict__ h, const float* __restrict__ U, const float* __restrict__ V,
    const int* __restrict__ cnt, const int* __restrict__ tok_list,
    const float* __restrict__ cf_list, float* __restrict__ out, const int slot)
{
    __shared__ float hb[2][EX_T][HPAD];     // phase A: h tiles; phase B: V tiles
    __shared__ float ub[2][RDIM][HPAD];     // phase A: U^T tiles; reduce scratch reuses ub[0]
    __shared__ float ylds[EX_T][RDIM + 1];
    __shared__ int   toks_s[EX_T];
    __shared__ float cfs_s[EX_T];

    const int tid = threadIdx.x;
    const int s = blockIdx.x;
    const int base = slot * NS + s;
    int count = cnt[base]; if (count > CAP) count = CAP;

    const int w = tid >> 6, lane = tid & 63;
    const int tg = w;                 // token group (phase A) = wave
    const int kg = (tid >> 4) & 3;    // k group
    const int js = tid & 15;          // j-split slice
    const int jgrp = tid >> 2, qq = tid & 3;   // U load mapping
    const int tB = tid >> 4, jg = tid & 15;    // phase B mapping

    const float* Ubase = U + (size_t)s * HD * RDIM;
    const float* Vbase = V + (size_t)s * RDIM * HD;

    #pragma unroll 1
    for (int ci = blockIdx.y; ci * EX_T < count; ci += gridDim.y) {
        const int nt = min(EX_T, count - ci * EX_T);
        if (tid < EX_T) {
            if (tid < nt) {
                toks_s[tid] = tok_list[base * CAP + ci * EX_T + tid];
                cfs_s[tid]  = cf_list[base * CAP + ci * EX_T + tid];
            } else { toks_s[tid] = 0; cfs_s[tid] = 0.f; }
        }
        __syncthreads();

        // ---- prime chunk 0: h rows via GLD, U^T via reg transpose ----
        #pragma unroll
        for (int r = 0; r < 4; ++r) {
            const int row = tg * 4 + r;
            gld16(h + (size_t)toks_s[row] * HD + lane * 4, &hb[0][row][0]);
        }
        float4 up[4];
        #pragma unroll
        for (int rr = 0; rr < 4; ++rr)
            up[rr] = *(const float4*)(Ubase + (size_t)(jgrp * 4 + rr) * RDIM + qq * 4);
        #pragma unroll
        for (int rr = 0; rr < 4; ++rr) {
            ub[0][qq * 4 + 0][jgrp * 4 + rr] = up[rr].x;
            ub[0][qq * 4 + 1][jgrp * 4 + rr] = up[rr].y;
            ub[0][qq * 4 + 2][jgrp * 4 + rr] = up[rr].z;
            ub[0][qq * 4 + 3][jgrp * 4 + rr] = up[rr].w;
        }
        __syncthreads();

        // ---- phase A ----
        float acc[4][4];
        #pragma unroll
        for (int a = 0; a < 4; ++a)
            #pragma unroll
            for (int b = 0; b < 4; ++b) acc[a][b] = 0.f;

        #pragma unroll 1
        for (int c = 0; c < 8; ++c) {
            const int cur = c & 1, nxt = cur ^ 1;
            if (c < 7) {   // prefetch next j-chunk: h async, U into regs
                #pragma unroll
                for (int r = 0; r < 4; ++r) {
                    const int row = tg * 4 + r;
                    gld16(h + (size_t)toks_s[row] * HD + (c + 1) * 256 + lane * 4,
                          &hb[nxt][row][0]);
                }
                #pragma unroll
                for (int rr = 0; rr < 4; ++rr)
                    up[rr] = *(const float4*)(Ubase +
                              (size_t)((c + 1) * 256 + jgrp * 4 + rr) * RDIM + qq * 4);
            }
            #pragma unroll
            for (int jq = 0; jq < 4; ++jq) {
                const int col = js * 4 + jq * 64;
                float4 hv0 = *(const float4*)&hb[cur][tg * 4 + 0][col];
                float4 hv1 = *(const float4*)&hb[cur][tg * 4 + 1][col];
                float4 hv2 = *(const float4*)&hb[cur][tg * 4 + 2][col];
                float4 hv3 = *(const float4*)&hb[cur][tg * 4 + 3][col];
                #pragma unroll
                for (int kk = 0; kk < 4; ++kk) {
                    const float4 uv = *(const float4*)&ub[cur][kg * 4 + kk][col];
                    acc[0][kk] += dot4(hv0, uv);
                    acc[1][kk] += dot4(hv1, uv);
                    acc[2][kk] += dot4(hv2, uv);
                    acc[3][kk] += dot4(hv3, uv);
                }
            }
            if (c < 7) {   // write prefetched U^T into next buffer
                #pragma unroll
                for (int rr = 0; rr < 4; ++rr) {
                    ub[nxt][qq * 4 + 0][jgrp * 4 + rr] = up[rr].x;
                    ub[nxt][qq * 4 + 1][jgrp * 4 + rr] = up[rr].y;
                    ub[nxt][qq * 4 + 2][jgrp * 4 + rr] = up[rr].z;
                    ub[nxt][qq * 4 + 3][jgrp * 4 + rr] = up[rr].w;
                }
            }
            __syncthreads();
        }

        // ---- 16-way j-split reduction (scratch reuses ub[0]; last A iter read ub[1]) ----
        float* red = &ub[0][0][0];
        #pragma unroll
        for (int tt = 0; tt < 4; ++tt)
            #pragma unroll
            for (int kk = 0; kk < 4; ++kk)
                red[js * HPAD + (tg * 4 + tt) * 16 + (kg * 4 + kk)] = acc[tt][kk];
        __syncthreads();
        {
            const int t = tid >> 4, k = tid & 15;
            float yv = 0.f;
            #pragma unroll
            for (int j2 = 0; j2 < 16; ++j2) yv += red[j2 * HPAD + t * 16 + k];
            ylds[t][k] = yv * cfs_s[t];   // gate+mult folded
        }
        __syncthreads();

        // ---- phase B ----
        #pragma unroll
        for (int r = 0; r < 4; ++r) {   // prime V chunk 0 (16 k-rows)
            const int row = tg * 4 + r;
            gld16(Vbase + (size_t)row * HD + lane * 4, &hb[0][row][0]);
        }
        __syncthreads();

        const bool act = tB < nt;
        #pragma unroll 1
        for (int c = 0; c < 8; ++c) {
            const int cur = c & 1, nxt = cur ^ 1;
            if (c < 7) {
                #pragma unroll
                for (int r = 0; r < 4; ++r) {
                    const int row = tg * 4 + r;
                    gld16(Vbase + (size_t)row * HD + (c + 1) * 256 + lane * 4,
                          &hb[nxt][row][0]);
                }
            }
            float* op = out + (size_t)toks_s[tB] * HD + c * 256 + jg * 4;
            float4 ov0, ov1, ov2, ov3;
            if (slot == 1 && act) {
                ov0 = *(const float4*)(op);
                ov1 = *(const float4*)(op + 64);
                ov2 = *(const float4*)(op + 128);
                ov3 = *(const float4*)(op + 192);
            }
            float4 o0 = {0,0,0,0}, o1 = {0,0,0,0}, o2 = {0,0,0,0}, o3 = {0,0,0,0};
            #pragma unroll
            for (int k = 0; k < RDIM; ++k) {
                const float yv = ylds[tB][k];
                fma4(o0, yv, *(const float4*)&hb[cur][k][jg * 4]);
                fma4(o1, yv, *(const float4*)&hb[cur][k][jg * 4 + 64]);
                fma4(o2, yv, *(const float4*)&hb[cur][k][jg * 4 + 128]);
                fma4(o3, yv, *(const float4*)&hb[cur][k][jg * 4 + 192]);
            }
            if (act) {
                if (slot == 1) {
                    o0.x += ov0.x; o0.y += ov0.y; o0.z += ov0.z; o0.w += ov0.w;
                    o1.x += ov1.x; o1.y += ov1.y; o1.z += ov1.z; o1.w += ov1.w;
                    o2.x += ov2.x; o2.y += ov2.y; o2.z += ov2.z; o2.w += ov2.w;
                    o3.x += ov3.x; o3.y += ov3.y; o3.z += ov3.z; o3.w += ov3.w;
                }
                *(float4*)(op)       = o0;
                *(float4*)(op + 64)  = o1;
                *(float4*)(op + 128) = o2;
                *(float4*)(op + 192) = o3;
            }
            __syncthreads();
        }
    }
}

extern "C" void kernel_launch(void* const* d_in, const int* in_sizes, int n_in,
                              void* d_out, int out_size, void* d_ws, size_t ws_size,
                              hipStream_t stream)
{
    const float* h    = (const float*)d_in[0];
    const float* Wr   = (const float*)d_in[1];
    const float* U    = (const float*)d_in[2];
    const float* V    = (const float*)d_in[3];
    const float* attr = (const float*)d_in[4];
    const float* Wa   = (const float*)d_in[5];
    float* outp = (float*)d_out;

    int*   cnt      = (int*)d_ws;
    int*   tok_list = (int*)((char*)d_ws + 256);
    float* cf_list  = (float*)((char*)d_ws + 256 + (size_t)64 * CAP * sizeof(int));

    hipLaunchKernelGGL(k_zero,   dim3(1),           dim3(64),  0, stream, cnt);
    hipLaunchKernelGGL(k_router, dim3(BT / RT_M),   dim3(256), 0, stream,
                       h, Wr, attr, Wa, cnt, tok_list, cf_list);
    hipLaunchKernelGGL(k_expert, dim3(NS, 24),      dim3(256), 0, stream,
                       h, U, V, cnt, tok_list, cf_list, outp, 0);
    hipLaunchKernelGGL(k_expert, dim3(NS, 24),      dim3(256), 0, stream,
                       h, U, V, cnt, tok_list, cf_list, outp, 1);
}

// Round 3
// 276.053 us; speedup vs baseline: 1.5755x; 1.5755x over previous
//
#include <hip/hip_runtime.h>
#include <cstddef>

#define BT   8192
#define HD   2048
#define NS   32
#define RDIM 16
#define AD   32
#define CAP  2048

// ---------------- workspace layout ----------------
// [0,256)                        int   cnt[64]           (slot*32 + schema)
// [256, +64*CAP*4)               int   tok_list[64][CAP]
// next 64*CAP*4                  float cf_list[64][CAP]
// next 4 MB                      float UT[32][16][2048]  (U transposed)
// next 8 MB                      float y_ws[64][CAP][16]

__device__ __forceinline__ float dot4(const float4 a, const float4 b) {
    return a.x * b.x + a.y * b.y + a.z * b.z + a.w * b.w;
}
__device__ __forceinline__ void fma4(float4& o, const float a, const float4 b) {
    o.x += a * b.x; o.y += a * b.y; o.z += a * b.z; o.w += a * b.w;
}

// ---------------- prep: zero counters + transpose U -> UT[s][k][j] ----------------
__global__ __launch_bounds__(256) void k_prep(const float* __restrict__ U,
                                              int* __restrict__ cnt,
                                              float* __restrict__ UT) {
    const int bx = blockIdx.x;
    if (bx == NS * 8) { if (threadIdx.x < 64) cnt[threadIdx.x] = 0; return; }
    const int s = bx >> 3, jc = bx & 7;
    const int j = jc * 256 + threadIdx.x;
    const float4* Up = (const float4*)(U + ((size_t)s * HD + j) * RDIM);
    const float4 a = Up[0], b = Up[1], c = Up[2], d = Up[3];
    float* Tp = UT + (size_t)s * RDIM * HD + j;
    Tp[0]       = a.x; Tp[HD]      = a.y; Tp[2*HD]   = a.z; Tp[3*HD]   = a.w;
    Tp[4*HD]    = b.x; Tp[5*HD]    = b.y; Tp[6*HD]   = b.z; Tp[7*HD]   = b.w;
    Tp[8*HD]    = c.x; Tp[9*HD]    = c.y; Tp[10*HD]  = c.z; Tp[11*HD]  = c.w;
    Tp[12*HD]   = d.x; Tp[13*HD]   = d.y; Tp[14*HD]  = d.z; Tp[15*HD]  = d.w;
}

// ---------------- router ----------------
// 1024 blocks x 8 tokens. Wave w covers schemas w*8..w*8+7 in 2 passes of 4.
// K split across 64 lanes (float4); h register-double-buffered; Wr lane-coalesced
// (L2-resident). Cross-lane butterfly reduce; one barrier; scalar tail as before.
__global__ __launch_bounds__(256) void k_router(
    const float* __restrict__ h, const float* __restrict__ Wr,
    const float* __restrict__ attr, const float* __restrict__ Wa,
    int* __restrict__ cnt, int* __restrict__ tok_list, float* __restrict__ cf_list)
{
    __shared__ float sc_s[8][NS + 1];
    const int tid = threadIdx.x, w = tid >> 6, lane = tid & 63;
    const int t0 = blockIdx.x * 8;

    #pragma unroll 1
    for (int g = 0; g < 2; ++g) {
        const int sb = w * 8 + g * 4;
        float vals[32];
        #pragma unroll
        for (int m = 0; m < 32; ++m) vals[m] = 0.f;

        float4 hA[8], hB[8];
        #pragma unroll
        for (int t = 0; t < 8; ++t)
            hA[t] = *(const float4*)(h + (size_t)(t0 + t) * HD + lane * 4);

        #pragma unroll 1
        for (int c = 0; c < 8; c += 2) {
            #pragma unroll
            for (int t = 0; t < 8; ++t)
                hB[t] = *(const float4*)(h + (size_t)(t0 + t) * HD + (c + 1) * 256 + lane * 4);
            #pragma unroll
            for (int sl = 0; sl < 4; ++sl) {
                const float4 wv = *(const float4*)(Wr + (size_t)(sb + sl) * HD + c * 256 + lane * 4);
                #pragma unroll
                for (int t = 0; t < 8; ++t) vals[t * 4 + sl] += dot4(hA[t], wv);
            }
            if (c < 6) {
                #pragma unroll
                for (int t = 0; t < 8; ++t)
                    hA[t] = *(const float4*)(h + (size_t)(t0 + t) * HD + (c + 2) * 256 + lane * 4);
            }
            #pragma unroll
            for (int sl = 0; sl < 4; ++sl) {
                const float4 wv = *(const float4*)(Wr + (size_t)(sb + sl) * HD + (c + 1) * 256 + lane * 4);
                #pragma unroll
                for (int t = 0; t < 8; ++t) vals[t * 4 + sl] += dot4(hB[t], wv);
            }
        }

        // reduce 32 values across 64 lanes: lane bits 0..4 select value halves
        // (pair-adjacent butterfly), bit 5 round sums duplicates.
        #pragma unroll
        for (int st = 0; st < 5; ++st) {
            const int d = 1 << st;
            const bool up = (lane & d) != 0;
            const int half = 16 >> st;
            #pragma unroll
            for (int i = 0; i < half; ++i) {
                const float lo = vals[2 * i], hi = vals[2 * i + 1];
                const float keep = up ? hi : lo, send = up ? lo : hi;
                vals[i] = keep + __shfl_xor(send, d, 64);
            }
        }
        vals[0] += __shfl_xor(vals[0], 32, 64);
        if (lane < 32)
            sc_s[lane >> 2][sb + (lane & 3)] = vals[0];   // m = t*4+sl = lane&31
    }
    __syncthreads();

    if (tid < 8) {
        const int t = tid;
        float m1 = -1e30f, m2 = -1e30f;
        int i1 = 0, i2 = 0;
        #pragma unroll 1
        for (int sI = 0; sI < NS; ++sI) {   // strict > keeps lowest index on ties (lax.top_k)
            const float v = sc_s[t][sI];
            if (v > m1) { m2 = m1; i2 = i1; m1 = v; i1 = sI; }
            else if (v > m2) { m2 = v; i2 = sI; }
        }
        float Z = 0.f;
        #pragma unroll 1
        for (int sI = 0; sI < NS; ++sI) Z += __expf(sc_s[t][sI] - m1);
        const float e2  = __expf(m2 - m1);
        // g = softmax(sc)*mask renormed by (sum + 1e-8): G_i = e_i / (e1+e2 + 1e-8*Z)
        const float den = 1.f + e2 + 1e-8f * Z;
        const float G1 = 1.f / den, G2 = e2 / den;
        float d1 = 0.f, d2 = 0.f;
        #pragma unroll 1
        for (int d = 0; d < AD; ++d) {
            d1 += attr[i1 * AD + d] * Wa[d];
            d2 += attr[i2 * AD + d] * Wa[d];
        }
        const float aw1 = 1.f / (1.f + __expf(-d1));
        const float aw2 = 1.f / (1.f + __expf(-d2));
        const float mult = 0.9f + 0.2f * (G1 * aw1 + G2 * aw2);
        const float c1 = G1 * mult, c2 = G2 * mult;
        const int gt = t0 + t;
        int p = atomicAdd(cnt + i1, 1);
        if (p < CAP) { tok_list[i1 * CAP + p] = gt; cf_list[i1 * CAP + p] = c1; }
        p = atomicAdd(cnt + NS + i2, 1);
        if (p < CAP) { tok_list[(NS + i2) * CAP + p] = gt; cf_list[(NS + i2) * CAP + p] = c2; }
    }
}

// ---------------- pass A: y[g][tok][k] = cf * (h[tok,:] @ U[s][:,k]) ----------------
// Both slots in one launch (g = 0..63). Wave = 4 tokens, K split across lanes,
// h register-dbuf (HBM gather, coalesced rows), UT lane-coalesced (L2, L1-shared
// across waves). No LDS, no barriers. Butterfly reduce -> coalesced 64-float write.
__global__ __launch_bounds__(256) void k_A(
    const float* __restrict__ h, const int* __restrict__ cnt,
    const int* __restrict__ tok_list, const float* __restrict__ cf_list,
    const float* __restrict__ UT, float* __restrict__ y_ws)
{
    const int g = blockIdx.x, s = g & (NS - 1);
    int count = cnt[g]; if (count > CAP) count = CAP;
    const int tid = threadIdx.x, w = tid >> 6, lane = tid & 63;
    const float* UTs = UT + (size_t)s * RDIM * HD;

    #pragma unroll 1
    for (int ci = blockIdx.y; ci * 16 < count; ci += gridDim.y) {
        int tok[4]; float cf[4];
        #pragma unroll
        for (int r = 0; r < 4; ++r) {
            const int idx = ci * 16 + w * 4 + r;
            const bool vld = idx < count;
            tok[r] = vld ? tok_list[g * CAP + idx] : 0;
            cf[r]  = vld ? cf_list[g * CAP + idx] : 0.f;
        }

        float vals[64];
        #pragma unroll
        for (int m = 0; m < 64; ++m) vals[m] = 0.f;

        float4 hA[4], hB[4];
        #pragma unroll
        for (int r = 0; r < 4; ++r)
            hA[r] = *(const float4*)(h + (size_t)tok[r] * HD + lane * 4);

        #pragma unroll 1
        for (int c = 0; c < 8; c += 2) {
            #pragma unroll
            for (int r = 0; r < 4; ++r)
                hB[r] = *(const float4*)(h + (size_t)tok[r] * HD + (c + 1) * 256 + lane * 4);
            #pragma unroll
            for (int kg = 0; kg < 4; ++kg) {
                #pragma unroll
                for (int q = 0; q < 4; ++q) {
                    const float4 uv = *(const float4*)(UTs + (size_t)(kg * 4 + q) * HD + c * 256 + lane * 4);
                    #pragma unroll
                    for (int r = 0; r < 4; ++r)
                        vals[r * 16 + kg * 4 + q] += dot4(hA[r], uv);
                }
            }
            if (c < 6) {
                #pragma unroll
                for (int r = 0; r < 4; ++r)
                    hA[r] = *(const float4*)(h + (size_t)tok[r] * HD + (c + 2) * 256 + lane * 4);
            }
            #pragma unroll
            for (int kg = 0; kg < 4; ++kg) {
                #pragma unroll
                for (int q = 0; q < 4; ++q) {
                    const float4 uv = *(const float4*)(UTs + (size_t)(kg * 4 + q) * HD + (c + 1) * 256 + lane * 4);
                    #pragma unroll
                    for (int r = 0; r < 4; ++r)
                        vals[r * 16 + kg * 4 + q] += dot4(hB[r], uv);
                }
            }
        }

        // reduce 64 values across 64 lanes (pair-adjacent butterfly): lane L ends
        // holding full sum of value m = L  (m = r*16 + k).
        #pragma unroll
        for (int st = 0; st < 6; ++st) {
            const int d = 1 << st;
            const bool up = (lane & d) != 0;
            const int half = 32 >> st;
            #pragma unroll
            for (int i = 0; i < half; ++i) {
                const float lo = vals[2 * i], hi = vals[2 * i + 1];
                const float keep = up ? hi : lo, send = up ? lo : hi;
                vals[i] = keep + __shfl_xor(send, d, 64);
            }
        }
        const int rsel = lane >> 4;
        const float cfv = rsel == 0 ? cf[0] : rsel == 1 ? cf[1] : rsel == 2 ? cf[2] : cf[3];
        y_ws[(size_t)g * (CAP * 16) + (size_t)(ci * 16 + w * 4) * 16 + lane] = vals[0] * cfv;
    }
}

// ---------------- pass B: out[tok][:] (+)= y[g][tok][:] @ V[s] ----------------
// Wave = 4 tokens; V lane-coalesced (L2-resident, L1-shared); y broadcast from 1KB
// LDS. slot 0 stores (argmax covers each token once), slot 1 non-atomic RMW add.
__global__ __launch_bounds__(256) void k_B(
    const float* __restrict__ V, const int* __restrict__ cnt,
    const int* __restrict__ tok_list, const float* __restrict__ y_ws,
    float* __restrict__ out, const int slot)
{
    __shared__ __align__(16) float ylds[256];
    __shared__ int toks_s[16];
    const int gsch = blockIdx.x;
    const int g = slot * NS + gsch;
    int count = cnt[g]; if (count > CAP) count = CAP;
    const int tid = threadIdx.x, w = tid >> 6, lane = tid & 63;
    const float* Vs = V + (size_t)gsch * RDIM * HD;

    #pragma unroll 1
    for (int ci = blockIdx.y; ci * 16 < count; ci += gridDim.y) {
        __syncthreads();   // protect ylds/toks_s from previous iteration's readers
        if (tid < 16)
            toks_s[tid] = (ci * 16 + tid < count) ? tok_list[g * CAP + ci * 16 + tid] : -1;
        ylds[tid] = y_ws[(size_t)g * (CAP * 16) + (size_t)ci * 256 + tid];
        __syncthreads();

        int tok[4]; bool act[4];
        #pragma unroll
        for (int r = 0; r < 4; ++r) {
            const int tv = toks_s[w * 4 + r];
            act[r] = tv >= 0; tok[r] = act[r] ? tv : 0;
        }

        #pragma unroll 1
        for (int c = 0; c < 8; ++c) {
            float4 ov[4];
            if (slot) {
                #pragma unroll
                for (int r = 0; r < 4; ++r)
                    if (act[r]) ov[r] = *(const float4*)(out + (size_t)tok[r] * HD + c * 256 + lane * 4);
            }
            float4 o[4];
            #pragma unroll
            for (int r = 0; r < 4; ++r) o[r] = make_float4(0.f, 0.f, 0.f, 0.f);

            #pragma unroll
            for (int kg = 0; kg < 4; ++kg) {
                float4 vv[4];
                #pragma unroll
                for (int q = 0; q < 4; ++q)
                    vv[q] = *(const float4*)(Vs + (size_t)(kg * 4 + q) * HD + c * 256 + lane * 4);
                #pragma unroll
                for (int r = 0; r < 4; ++r) {
                    const float4 yv = *(const float4*)&ylds[(w * 4 + r) * 16 + kg * 4];
                    fma4(o[r], yv.x, vv[0]); fma4(o[r], yv.y, vv[1]);
                    fma4(o[r], yv.z, vv[2]); fma4(o[r], yv.w, vv[3]);
                }
            }
            #pragma unroll
            for (int r = 0; r < 4; ++r) {
                if (act[r]) {
                    float* op = out + (size_t)tok[r] * HD + c * 256 + lane * 4;
                    if (slot) {
                        o[r].x += ov[r].x; o[r].y += ov[r].y;
                        o[r].z += ov[r].z; o[r].w += ov[r].w;
                    }
                    *(float4*)op = o[r];
                }
            }
        }
    }
}

extern "C" void kernel_launch(void* const* d_in, const int* in_sizes, int n_in,
                              void* d_out, int out_size, void* d_ws, size_t ws_size,
                              hipStream_t stream)
{
    const float* h    = (const float*)d_in[0];
    const float* Wr   = (const float*)d_in[1];
    const float* U    = (const float*)d_in[2];
    const float* V    = (const float*)d_in[3];
    const float* attr = (const float*)d_in[4];
    const float* Wa   = (const float*)d_in[5];
    float* outp = (float*)d_out;

    char* ws = (char*)d_ws;
    int*   cnt      = (int*)ws;
    int*   tok_list = (int*)(ws + 256);
    float* cf_list  = (float*)(ws + 256 + (size_t)64 * CAP * 4);
    float* UT       = (float*)(ws + 256 + (size_t)2 * 64 * CAP * 4);
    float* y_ws     = UT + (size_t)NS * RDIM * HD;

    hipLaunchKernelGGL(k_prep,   dim3(NS * 8 + 1),  dim3(256), 0, stream, U, cnt, UT);
    hipLaunchKernelGGL(k_router, dim3(BT / 8),      dim3(256), 0, stream,
                       h, Wr, attr, Wa, cnt, tok_list, cf_list);
    hipLaunchKernelGGL(k_A,      dim3(64, 32),      dim3(256), 0, stream,
                       h, cnt, tok_list, cf_list, UT, y_ws);
    hipLaunchKernelGGL(k_B,      dim3(NS, 32),      dim3(256), 0, stream,
                       V, cnt, tok_list, y_ws, outp, 0);
    hipLaunchKernelGGL(k_B,      dim3(NS, 32),      dim3(256), 0, stream,
                       V, cnt, tok_list, y_ws, outp, 1);
}